// Round 1
// baseline (290.697 us; speedup 1.0000x reference)
//
#include <hip/hip_runtime.h>
#include <hip/hip_bf16.h>
#include <stdint.h>

// Causal self-attention, B=2 T=2048 C=1024 H=16 D=64, scale = 1/sqrt(C) = 1/32.
// Pipeline: cvt(fp32->bf16) -> fused QKV GEMM (bf16 MFMA) -> flash attention -> out GEMM.

typedef __bf16 bf16_t;
typedef __bf16 bf16x8 __attribute__((ext_vector_type(8)));
typedef float f32x4 __attribute__((ext_vector_type(4)));
typedef unsigned short u16x8 __attribute__((ext_vector_type(8)));
typedef unsigned short u16x4 __attribute__((ext_vector_type(4)));

#define MFMA(a, b, c) __builtin_amdgcn_mfma_f32_16x16x32_bf16((a), (b), (c), 0, 0, 0)

// ---------------------------------------------------------------- convert ----
__global__ __launch_bounds__(256) void cvt_f32_to_bf16(const float* __restrict__ in,
                                                       bf16_t* __restrict__ out, int n) {
  int i = (blockIdx.x * 256 + threadIdx.x) * 8;
  if (i + 8 > n) return;
  const float4 a = *reinterpret_cast<const float4*>(in + i);
  const float4 b = *reinterpret_cast<const float4*>(in + i + 4);
  bf16x8 o;
  o[0] = (bf16_t)a.x; o[1] = (bf16_t)a.y; o[2] = (bf16_t)a.z; o[3] = (bf16_t)a.w;
  o[4] = (bf16_t)b.x; o[5] = (bf16_t)b.y; o[6] = (bf16_t)b.z; o[7] = (bf16_t)b.w;
  *reinterpret_cast<bf16x8*>(out + i) = o;
}

// ------------------------------------------------------------- QKV GEMM ------
// C[m][n] = sum_k X[m][k] * W[n][k]   (x @ W.T), M=4096, N=1024, K=1024.
// 128x128 tile, BK=64, 4 waves (2x2), each wave 64x64 = 4x4 frags of 16x16x32.
// z = blockIdx.z selects {Wq,Wk,Wv}; epilogue scatters to attention layouts:
//   z=0: Q[b][h][t][d] *= 1/32   z=1: K[b][h][t][d]   z=2: Vt[b][h][d][t]
__global__ __launch_bounds__(256, 2) void qkv_gemm(
    const bf16_t* __restrict__ X, const bf16_t* __restrict__ Wq,
    const bf16_t* __restrict__ Wk, const bf16_t* __restrict__ Wv,
    bf16_t* __restrict__ Q, bf16_t* __restrict__ Ko, bf16_t* __restrict__ Vt) {
  constexpr int Kdim = 1024;
  const int z = blockIdx.z;
  const bf16_t* __restrict__ W = (z == 0) ? Wq : (z == 1) ? Wk : Wv;

  __shared__ __align__(16) bf16_t As[128][64];
  __shared__ __align__(16) bf16_t Bs[128][64];

  const int tid = threadIdx.x;
  const int lane = tid & 63;
  const int w = tid >> 6;
  const int wr = w >> 1, wc = w & 1;
  const int ln = lane & 15, lh = lane >> 4;
  const int brow = blockIdx.y * 128;
  const int bcol = blockIdx.x * 128;

  f32x4 acc[4][4] = {};

  for (int k0 = 0; k0 < Kdim; k0 += 64) {
#pragma unroll
    for (int s = 0; s < 4; ++s) {
      const int e = (s * 256 + tid) * 8;
      const int r = e >> 6, c = e & 63;
      *reinterpret_cast<u16x8*>(&As[r][c]) =
          *reinterpret_cast<const u16x8*>(&X[(size_t)(brow + r) * Kdim + k0 + c]);
      *reinterpret_cast<u16x8*>(&Bs[r][c]) =
          *reinterpret_cast<const u16x8*>(&W[(size_t)(bcol + r) * Kdim + k0 + c]);
    }
    __syncthreads();
#pragma unroll
    for (int kk = 0; kk < 2; ++kk) {
      bf16x8 af[4], bfm[4];
#pragma unroll
      for (int i = 0; i < 4; ++i)
        af[i] = *reinterpret_cast<const bf16x8*>(&As[wr * 64 + i * 16 + ln][kk * 32 + lh * 8]);
#pragma unroll
      for (int j = 0; j < 4; ++j)
        bfm[j] = *reinterpret_cast<const bf16x8*>(&Bs[wc * 64 + j * 16 + ln][kk * 32 + lh * 8]);
#pragma unroll
      for (int i = 0; i < 4; ++i)
#pragma unroll
        for (int j = 0; j < 4; ++j)
          acc[i][j] = MFMA(af[i], bfm[j], acc[i][j]);
    }
    __syncthreads();
  }

#pragma unroll
  for (int i = 0; i < 4; ++i) {
    const int m0 = brow + wr * 64 + i * 16 + lh * 4;  // token index of reg r=0
    const int b = m0 >> 11;
    const int t0 = m0 & 2047;
#pragma unroll
    for (int j = 0; j < 4; ++j) {
      const int n = bcol + wc * 64 + j * 16 + ln;  // output channel
      const int h = n >> 6, d = n & 63;
      if (z == 2) {
        // V transposed: [b][h][d][t]; 4 regs = 4 consecutive t -> one 8B store
        u16x4 pk;
#pragma unroll
        for (int r = 0; r < 4; ++r)
          pk[r] = __builtin_bit_cast(unsigned short, (bf16_t)acc[i][j][r]);
        *reinterpret_cast<u16x4*>(&Vt[(size_t)((b * 16 + h) * 64 + d) * 2048 + t0]) = pk;
      } else {
        bf16_t* __restrict__ dst = (z == 0) ? Q : Ko;
        const float sc = (z == 0) ? 0.03125f : 1.0f;  // fold softmax scale into Q (2^-5, exact)
#pragma unroll
        for (int r = 0; r < 4; ++r)
          dst[(size_t)((b * 16 + h) * 2048 + t0 + r) * 64 + d] = (bf16_t)(acc[i][j][r] * sc);
      }
    }
  }
}

// --------------------------------------------------------- flash attention ---
// Per block: one (b,h), 128 q-rows (4 waves x 32 rows). K/V tiles of 64 keys in
// shared LDS; per-wave online softmax, P re-laid-out through per-wave LDS.
__global__ __launch_bounds__(256, 2) void attn_fwd(
    const bf16_t* __restrict__ q,    // [BH][T][64], pre-scaled by 1/32
    const bf16_t* __restrict__ kmat, // [BH][T][64]
    const bf16_t* __restrict__ vt,   // [BH][64][T]
    bf16_t* __restrict__ o)          // [B*T][1024] : o[(b*2048+t)*1024 + h*64 + d]
{
  const int bh = blockIdx.y;
  const int h = bh & 15, b = bh >> 4;
  const int qblk = blockIdx.x;
  const int tid = threadIdx.x, w = tid >> 6, lane = tid & 63;
  const int ln = lane & 15, lh = lane >> 4;

  __shared__ __align__(16) bf16_t Ks[64][64];   // [key][d]
  __shared__ __align__(16) bf16_t Vts[64][64];  // [d][key]
  __shared__ __align__(16) bf16_t Ps[4][32][64];// per-wave [qrow][key]

  const size_t base = (size_t)bh * 2048 * 64;
  const int q0 = qblk * 128 + w * 32;

  // Q fragments, held in registers for the whole kernel
  bf16x8 qf[2][2];
#pragma unroll
  for (int i = 0; i < 2; ++i)
#pragma unroll
    for (int kk = 0; kk < 2; ++kk)
      qf[i][kk] = *reinterpret_cast<const bf16x8*>(
          &q[base + (size_t)(q0 + i * 16 + ln) * 64 + kk * 32 + lh * 8]);

  f32x4 o_acc[2][4] = {};
  float m_s[2][4], l_s[2][4];
#pragma unroll
  for (int i = 0; i < 2; ++i)
#pragma unroll
    for (int r = 0; r < 4; ++r) { m_s[i][r] = -1e30f; l_s[i][r] = 0.0f; }

  const int ntiles = qblk * 2 + 2;  // causal: keys up to block's last q-row
  for (int kt = 0; kt < ntiles; ++kt) {
    const int k0 = kt * 64;
    __syncthreads();  // previous tile's LDS reads done
#pragma unroll
    for (int s = 0; s < 2; ++s) {
      const int e = (s * 256 + tid) * 8;
      const int r = e >> 6, c = e & 63;
      *reinterpret_cast<u16x8*>(&Ks[r][c]) =
          *reinterpret_cast<const u16x8*>(&kmat[base + (size_t)(k0 + r) * 64 + c]);
      *reinterpret_cast<u16x8*>(&Vts[r][c]) =
          *reinterpret_cast<const u16x8*>(&vt[base + (size_t)r * 2048 + k0 + c]);
    }
    __syncthreads();

    // S = Q * K^T (already scaled): 32 x 64
    f32x4 sfr[2][4] = {};
#pragma unroll
    for (int kk = 0; kk < 2; ++kk) {
      bf16x8 kf[4];
#pragma unroll
      for (int j = 0; j < 4; ++j)
        kf[j] = *reinterpret_cast<const bf16x8*>(&Ks[j * 16 + ln][kk * 32 + lh * 8]);
#pragma unroll
      for (int i = 0; i < 2; ++i)
#pragma unroll
        for (int j = 0; j < 4; ++j)
          sfr[i][j] = MFMA(qf[i][kk], kf[j], sfr[i][j]);
    }

    // causal mask + online softmax (wave-parallel: 16-lane shfl_xor reduce)
    float alpha[2][4];
#pragma unroll
    for (int i = 0; i < 2; ++i) {
#pragma unroll
      for (int r = 0; r < 4; ++r) {
        const int qg = q0 + i * 16 + lh * 4 + r;  // this row's global q index
        float mx = -1e30f;
#pragma unroll
        for (int j = 0; j < 4; ++j) {
          const int key = k0 + j * 16 + ln;
          float sv = (key <= qg) ? sfr[i][j][r] : -1e30f;
          sfr[i][j][r] = sv;
          mx = fmaxf(mx, sv);
        }
#pragma unroll
        for (int off = 1; off < 16; off <<= 1) mx = fmaxf(mx, __shfl_xor(mx, off));
        const float mnew = fmaxf(m_s[i][r], mx);
        const float a = __expf(m_s[i][r] - mnew);
        m_s[i][r] = mnew;
        float rs = 0.0f;
#pragma unroll
        for (int j = 0; j < 4; ++j) {
          const float p = __expf(sfr[i][j][r] - mnew);
          sfr[i][j][r] = p;
          rs += p;
        }
#pragma unroll
        for (int off = 1; off < 16; off <<= 1) rs += __shfl_xor(rs, off);
        l_s[i][r] = l_s[i][r] * a + rs;
        alpha[i][r] = a;
      }
    }

    // P -> per-wave LDS (re-layout for PV A-fragments)
#pragma unroll
    for (int i = 0; i < 2; ++i)
#pragma unroll
      for (int j = 0; j < 4; ++j)
#pragma unroll
        for (int r = 0; r < 4; ++r)
          Ps[w][i * 16 + lh * 4 + r][j * 16 + ln] = (bf16_t)sfr[i][j][r];
    asm volatile("s_waitcnt lgkmcnt(0)" ::: "memory");  // wave-internal write->read fence

    // rescale O
#pragma unroll
    for (int i = 0; i < 2; ++i)
#pragma unroll
      for (int j = 0; j < 4; ++j)
#pragma unroll
        for (int r = 0; r < 4; ++r) o_acc[i][j][r] *= alpha[i][r];

    // O += P * V
#pragma unroll
    for (int kk = 0; kk < 2; ++kk) {
      bf16x8 pa[2], vf[4];
#pragma unroll
      for (int i = 0; i < 2; ++i)
        pa[i] = *reinterpret_cast<const bf16x8*>(&Ps[w][i * 16 + ln][kk * 32 + lh * 8]);
#pragma unroll
      for (int j = 0; j < 4; ++j)
        vf[j] = *reinterpret_cast<const bf16x8*>(&Vts[j * 16 + ln][kk * 32 + lh * 8]);
#pragma unroll
      for (int i = 0; i < 2; ++i)
#pragma unroll
        for (int j = 0; j < 4; ++j)
          o_acc[i][j] = MFMA(pa[i], vf[j], o_acc[i][j]);
    }
  }

  // normalize + store to [B*T][1024]
#pragma unroll
  for (int i = 0; i < 2; ++i) {
#pragma unroll
    for (int r = 0; r < 4; ++r) {
      const float inv = 1.0f / l_s[i][r];
      const int t = q0 + i * 16 + lh * 4 + r;
#pragma unroll
      for (int j = 0; j < 4; ++j) {
        const int d = j * 16 + ln;
        o[(size_t)(b * 2048 + t) * 1024 + h * 64 + d] = (bf16_t)(o_acc[i][j][r] * inv);
      }
    }
  }
}

// ------------------------------------------------------------- out GEMM ------
// Y[m][n] = sum_k O[m][k] * Wo[n][k] + bias[n], fp32 out.
__global__ __launch_bounds__(256, 2) void out_gemm(
    const bf16_t* __restrict__ X, const bf16_t* __restrict__ W,
    const float* __restrict__ bias, float* __restrict__ Y) {
  constexpr int Kdim = 1024;
  __shared__ __align__(16) bf16_t As[128][64];
  __shared__ __align__(16) bf16_t Bs[128][64];

  const int tid = threadIdx.x;
  const int lane = tid & 63;
  const int w = tid >> 6;
  const int wr = w >> 1, wc = w & 1;
  const int ln = lane & 15, lh = lane >> 4;
  const int brow = blockIdx.y * 128;
  const int bcol = blockIdx.x * 128;

  f32x4 acc[4][4] = {};

  for (int k0 = 0; k0 < Kdim; k0 += 64) {
#pragma unroll
    for (int s = 0; s < 4; ++s) {
      const int e = (s * 256 + tid) * 8;
      const int r = e >> 6, c = e & 63;
      *reinterpret_cast<u16x8*>(&As[r][c]) =
          *reinterpret_cast<const u16x8*>(&X[(size_t)(brow + r) * Kdim + k0 + c]);
      *reinterpret_cast<u16x8*>(&Bs[r][c]) =
          *reinterpret_cast<const u16x8*>(&W[(size_t)(bcol + r) * Kdim + k0 + c]);
    }
    __syncthreads();
#pragma unroll
    for (int kk = 0; kk < 2; ++kk) {
      bf16x8 af[4], bfm[4];
#pragma unroll
      for (int i = 0; i < 4; ++i)
        af[i] = *reinterpret_cast<const bf16x8*>(&As[wr * 64 + i * 16 + ln][kk * 32 + lh * 8]);
#pragma unroll
      for (int j = 0; j < 4; ++j)
        bfm[j] = *reinterpret_cast<const bf16x8*>(&Bs[wc * 64 + j * 16 + ln][kk * 32 + lh * 8]);
#pragma unroll
      for (int i = 0; i < 4; ++i)
#pragma unroll
        for (int j = 0; j < 4; ++j)
          acc[i][j] = MFMA(af[i], bfm[j], acc[i][j]);
    }
    __syncthreads();
  }

#pragma unroll
  for (int i = 0; i < 4; ++i) {
    const int m0 = brow + wr * 64 + i * 16 + lh * 4;
#pragma unroll
    for (int j = 0; j < 4; ++j) {
      const int n = bcol + wc * 64 + j * 16 + ln;
      const float bv = bias[n];
#pragma unroll
      for (int r = 0; r < 4; ++r)
        Y[(size_t)(m0 + r) * 1024 + n] = acc[i][j][r] + bv;
    }
  }
}

// ---------------------------------------------------------------- launch -----
extern "C" void kernel_launch(void* const* d_in, const int* in_sizes, int n_in,
                              void* d_out, int out_size, void* d_ws, size_t ws_size,
                              hipStream_t stream) {
  const float* x  = (const float*)d_in[0];
  const float* Wq = (const float*)d_in[1];
  const float* Wk = (const float*)d_in[2];
  const float* Wv = (const float*)d_in[3];
  const float* Wo = (const float*)d_in[4];
  const float* bo = (const float*)d_in[5];

  char* ws = (char*)d_ws;
  bf16_t* xb  = (bf16_t*)(ws);                        // 8 MB  [4096][1024]
  bf16_t* wqb = (bf16_t*)(ws + (size_t)(8u  << 20));  // 2 MB
  bf16_t* wkb = (bf16_t*)(ws + (size_t)(10u << 20));  // 2 MB
  bf16_t* wvb = (bf16_t*)(ws + (size_t)(12u << 20));  // 2 MB
  bf16_t* wob = (bf16_t*)(ws + (size_t)(14u << 20));  // 2 MB
  bf16_t* qb  = (bf16_t*)(ws + (size_t)(16u << 20));  // 8 MB  [2][16][2048][64]
  bf16_t* kb  = (bf16_t*)(ws + (size_t)(24u << 20));  // 8 MB  [2][16][2048][64]
  bf16_t* vtb = (bf16_t*)(ws + (size_t)(32u << 20));  // 8 MB  [2][16][64][2048]
  bf16_t* ob  = (bf16_t*)(ws + (size_t)(40u << 20));  // 8 MB  [4096][1024]

  cvt_f32_to_bf16<<<2048, 256, 0, stream>>>(x, xb, 4096 * 1024);
  cvt_f32_to_bf16<<<512, 256, 0, stream>>>(Wq, wqb, 1024 * 1024);
  cvt_f32_to_bf16<<<512, 256, 0, stream>>>(Wk, wkb, 1024 * 1024);
  cvt_f32_to_bf16<<<512, 256, 0, stream>>>(Wv, wvb, 1024 * 1024);
  cvt_f32_to_bf16<<<512, 256, 0, stream>>>(Wo, wob, 1024 * 1024);

  qkv_gemm<<<dim3(8, 32, 3), 256, 0, stream>>>(xb, wqb, wkb, wvb, qb, kb, vtb);
  attn_fwd<<<dim3(16, 32), 256, 0, stream>>>(qb, kb, vtb, ob);
  out_gemm<<<dim3(8, 32), 256, 0, stream>>>(ob, wob, bo, (float*)d_out);
}

// Round 2
// 227.306 us; speedup vs baseline: 1.2789x; 1.2789x over previous
//
#include <hip/hip_runtime.h>
#include <hip/hip_bf16.h>
#include <stdint.h>

// Causal self-attention, B=2 T=2048 C=1024 H=16 D=64, scale = 1/sqrt(C) = 1/32.
// cvt(fp32->bf16) -> fused QKV GEMM (bf16 MFMA, global_load_lds staging)
// -> flash attention (swizzled LDS, balanced grid) -> out GEMM.

typedef __bf16 bf16_t;
typedef __bf16 bf16x8 __attribute__((ext_vector_type(8)));
typedef float f32x4 __attribute__((ext_vector_type(4)));
typedef unsigned short u16x8 __attribute__((ext_vector_type(8)));
typedef unsigned short u16x4 __attribute__((ext_vector_type(4)));

#define MFMA(a, b, c) __builtin_amdgcn_mfma_f32_16x16x32_bf16((a), (b), (c), 0, 0, 0)

// async global->LDS, 16B per lane; LDS dest = uniform base + lane*16
__device__ __forceinline__ void gload_lds16(const void* g, void* l) {
  __builtin_amdgcn_global_load_lds(
      (const __attribute__((address_space(1))) void*)g,
      (__attribute__((address_space(3))) void*)l, 16, 0, 0);
}

// ---------------------------------------------------------------- convert ----
__global__ __launch_bounds__(256) void cvt_f32_to_bf16(const float* __restrict__ in,
                                                       bf16_t* __restrict__ out, int n) {
  int i = (blockIdx.x * 256 + threadIdx.x) * 8;
  if (i + 8 > n) return;
  const float4 a = *reinterpret_cast<const float4*>(in + i);
  const float4 b = *reinterpret_cast<const float4*>(in + i + 4);
  bf16x8 o;
  o[0] = (bf16_t)a.x; o[1] = (bf16_t)a.y; o[2] = (bf16_t)a.z; o[3] = (bf16_t)a.w;
  o[4] = (bf16_t)b.x; o[5] = (bf16_t)b.y; o[6] = (bf16_t)b.z; o[7] = (bf16_t)b.w;
  *reinterpret_cast<bf16x8*>(out + i) = o;
}

__global__ __launch_bounds__(256) void cvt4_f32_to_bf16(
    const float* __restrict__ i0, const float* __restrict__ i1,
    const float* __restrict__ i2, const float* __restrict__ i3,
    bf16_t* __restrict__ o0, bf16_t* __restrict__ o1,
    bf16_t* __restrict__ o2, bf16_t* __restrict__ o3) {
  const float* in; bf16_t* out;
  switch (blockIdx.y) {
    case 0: in = i0; out = o0; break;
    case 1: in = i1; out = o1; break;
    case 2: in = i2; out = o2; break;
    default: in = i3; out = o3; break;
  }
  int i = (blockIdx.x * 256 + threadIdx.x) * 8;
  const float4 a = *reinterpret_cast<const float4*>(in + i);
  const float4 b = *reinterpret_cast<const float4*>(in + i + 4);
  bf16x8 o;
  o[0] = (bf16_t)a.x; o[1] = (bf16_t)a.y; o[2] = (bf16_t)a.z; o[3] = (bf16_t)a.w;
  o[4] = (bf16_t)b.x; o[5] = (bf16_t)b.y; o[6] = (bf16_t)b.z; o[7] = (bf16_t)b.w;
  *reinterpret_cast<bf16x8*>(out + i) = o;
}

// ------------------------------------------------------------- QKV GEMM ------
// C[m][n] = sum_k X[m][k] * W[n][k]   (x @ W.T), M=4096, N=1024, K=1024.
// 128x128 tile, BK=64, 4 waves (2x2); staging via global_load_lds width=16.
__global__ __launch_bounds__(256, 2) void qkv_gemm(
    const bf16_t* __restrict__ X, const bf16_t* __restrict__ Wq,
    const bf16_t* __restrict__ Wk, const bf16_t* __restrict__ Wv,
    bf16_t* __restrict__ Q, bf16_t* __restrict__ Ko, bf16_t* __restrict__ Vt) {
  constexpr int Kdim = 1024;
  const int z = blockIdx.z;
  const bf16_t* __restrict__ W = (z == 0) ? Wq : (z == 1) ? Wk : Wv;

  __shared__ __align__(16) bf16_t As[128][64];
  __shared__ __align__(16) bf16_t Bs[128][64];

  const int tid = threadIdx.x;
  const int lane = tid & 63;
  const int w = tid >> 6;
  const int wr = w >> 1, wc = w & 1;
  const int ln = lane & 15, lh = lane >> 4;
  const int brow = blockIdx.y * 128;
  const int bcol = blockIdx.x * 128;

  // per-lane staging geometry (source side); LDS dest is linear
  const int soff = (w * 4) * 1024 + lane * 16;  // byte offset of this wave's first chunk

  f32x4 acc[4][4] = {};

  for (int k0 = 0; k0 < Kdim; k0 += 64) {
#pragma unroll
    for (int s = 0; s < 4; ++s) {
      const int off = soff + s * 1024;
      const int row = off >> 7, colb = off & 127;
      gload_lds16((const char*)X + ((size_t)(brow + row) * Kdim + k0) * 2 + colb,
                  (char*)&As[0][0] + (w * 4 + s) * 1024);
      gload_lds16((const char*)W + ((size_t)(bcol + row) * Kdim + k0) * 2 + colb,
                  (char*)&Bs[0][0] + (w * 4 + s) * 1024);
    }
    __syncthreads();
#pragma unroll
    for (int kk = 0; kk < 2; ++kk) {
      bf16x8 af[4], bfm[4];
#pragma unroll
      for (int i = 0; i < 4; ++i)
        af[i] = *reinterpret_cast<const bf16x8*>(&As[wr * 64 + i * 16 + ln][kk * 32 + lh * 8]);
#pragma unroll
      for (int j = 0; j < 4; ++j)
        bfm[j] = *reinterpret_cast<const bf16x8*>(&Bs[wc * 64 + j * 16 + ln][kk * 32 + lh * 8]);
#pragma unroll
      for (int i = 0; i < 4; ++i)
#pragma unroll
        for (int j = 0; j < 4; ++j)
          acc[i][j] = MFMA(af[i], bfm[j], acc[i][j]);
    }
    __syncthreads();
  }

#pragma unroll
  for (int i = 0; i < 4; ++i) {
    const int m0 = brow + wr * 64 + i * 16 + lh * 4;  // token index of reg r=0
    const int b = m0 >> 11;
    const int t0 = m0 & 2047;
#pragma unroll
    for (int j = 0; j < 4; ++j) {
      const int n = bcol + wc * 64 + j * 16 + ln;  // output channel
      const int h = n >> 6, d = n & 63;
      if (z == 2) {
        u16x4 pk;
#pragma unroll
        for (int r = 0; r < 4; ++r)
          pk[r] = __builtin_bit_cast(unsigned short, (bf16_t)acc[i][j][r]);
        *reinterpret_cast<u16x4*>(&Vt[(size_t)((b * 16 + h) * 64 + d) * 2048 + t0]) = pk;
      } else {
        bf16_t* __restrict__ dst = (z == 0) ? Q : Ko;
        const float sc = (z == 0) ? 0.03125f : 1.0f;  // fold 1/sqrt(C)=2^-5 into Q
#pragma unroll
        for (int r = 0; r < 4; ++r)
          dst[(size_t)((b * 16 + h) * 2048 + t0 + r) * 64 + d] = (bf16_t)(acc[i][j][r] * sc);
      }
    }
  }
}

// --------------------------------------------------------- flash attention ---
// grid (x=bh 32, y=qblk 32); block = 4 waves x 16 q-rows = 64 q-rows.
// K/V tiles (64 keys) staged via global_load_lds with pre-swizzled source;
// reads swizzled (T2). P routed through swizzled per-wave LDS.
#define SWZK(r, c) ((c) ^ (((r) & 7) << 3))        // element-space, 128B rows
#define SWZP(r, c) ((c) ^ ((((r) >> 2) & 3) << 4)) // element-space, P buffer
__global__ __launch_bounds__(256, 4) void attn_fwd(
    const bf16_t* __restrict__ q,    // [BH][T][64], pre-scaled by 1/32
    const bf16_t* __restrict__ kmat, // [BH][T][64]
    const bf16_t* __restrict__ vt,   // [BH][64][T]
    bf16_t* __restrict__ o)          // [B*T][1024]
{
  const int bh = blockIdx.x;
  const int h = bh & 15, b = bh >> 4;
  const int qblk = blockIdx.y;
  const int tid = threadIdx.x, w = tid >> 6, lane = tid & 63;
  const int ln = lane & 15, lh = lane >> 4;

  __shared__ __align__(16) bf16_t Ks[64][64];     // [key][c], swizzled
  __shared__ __align__(16) bf16_t Vts[64][64];    // [d][key], swizzled
  __shared__ __align__(16) bf16_t Ps[4][16][64];  // per-wave [qrow][key], swizzled

  const size_t base = (size_t)bh * 2048 * 64;
  const int q0 = qblk * 64 + w * 16;

  // Q fragments in registers for the whole kernel
  bf16x8 qf[2];
#pragma unroll
  for (int kk = 0; kk < 2; ++kk)
    qf[kk] = *reinterpret_cast<const bf16x8*>(
        &q[base + (size_t)(q0 + ln) * 64 + kk * 32 + lh * 8]);

  f32x4 o_acc[4] = {};
  float m_s[4], l_s[4];
#pragma unroll
  for (int r = 0; r < 4; ++r) { m_s[r] = -1e30f; l_s[r] = 0.0f; }

  // staging geometry: 16 x 1KB chunks (Ks: 0-7, Vts: 8-15), wave w -> chunks w*4..w*4+3
  const int ck0 = w * 4;

  const int ntiles = qblk + 1;
  for (int kt = 0; kt < ntiles; ++kt) {
    const int k0 = kt * 64;
    __syncthreads();  // previous tile's LDS reads done
#pragma unroll
    for (int s = 0; s < 4; ++s) {
      const int c = ck0 + s;
      const int off = (c & 7) * 1024 + lane * 16;
      const int row = off >> 7;
      const int colb = (off & 127) ^ ((row & 7) << 4);  // pre-swizzled source
      if (c < 8)
        gload_lds16((const char*)kmat + (base + (size_t)(k0 + row) * 64) * 2 + colb,
                    (char*)&Ks[0][0] + (c & 7) * 1024);
      else
        gload_lds16((const char*)vt + (base + (size_t)row * 2048 + k0) * 2 + colb,
                    (char*)&Vts[0][0] + (c & 7) * 1024);
    }
    __syncthreads();

    // S = Q * K^T (pre-scaled): 16 x 64 per wave
    f32x4 sfr[4] = {};
#pragma unroll
    for (int kk = 0; kk < 2; ++kk) {
      bf16x8 kf[4];
#pragma unroll
      for (int j = 0; j < 4; ++j) {
        const int kr = j * 16 + ln;
        kf[j] = *reinterpret_cast<const bf16x8*>(&Ks[kr][SWZK(kr, kk * 32 + lh * 8)]);
      }
#pragma unroll
      for (int j = 0; j < 4; ++j)
        sfr[j] = MFMA(qf[kk], kf[j], sfr[j]);
    }

    // causal mask + online softmax (16-lane shfl_xor reduce per q-row)
    float alpha[4];
#pragma unroll
    for (int r = 0; r < 4; ++r) {
      const int qg = q0 + lh * 4 + r;  // this row's global q index
      float mx = -1e30f;
#pragma unroll
      for (int j = 0; j < 4; ++j) {
        const int key = k0 + j * 16 + ln;
        float sv = (key <= qg) ? sfr[j][r] : -1e30f;
        sfr[j][r] = sv;
        mx = fmaxf(mx, sv);
      }
#pragma unroll
      for (int off = 1; off < 16; off <<= 1) mx = fmaxf(mx, __shfl_xor(mx, off));
      const float mnew = fmaxf(m_s[r], mx);
      const float a = __expf(m_s[r] - mnew);
      m_s[r] = mnew;
      float rs = 0.0f;
#pragma unroll
      for (int j = 0; j < 4; ++j) {
        const float p = __expf(sfr[j][r] - mnew);
        sfr[j][r] = p;
        rs += p;
      }
#pragma unroll
      for (int off = 1; off < 16; off <<= 1) rs += __shfl_xor(rs, off);
      l_s[r] = l_s[r] * a + rs;
      alpha[r] = a;
    }

    // P -> per-wave swizzled LDS (re-layout for PV A-fragments)
#pragma unroll
    for (int j = 0; j < 4; ++j)
#pragma unroll
      for (int r = 0; r < 4; ++r) {
        const int pr = lh * 4 + r;
        Ps[w][pr][SWZP(pr, j * 16 + ln)] = (bf16_t)sfr[j][r];
      }
    asm volatile("s_waitcnt lgkmcnt(0)" ::: "memory");  // wave-internal write->read fence

    // rescale O
#pragma unroll
    for (int j = 0; j < 4; ++j)
#pragma unroll
      for (int r = 0; r < 4; ++r) o_acc[j][r] *= alpha[r];

    // O += P * V
#pragma unroll
    for (int kk = 0; kk < 2; ++kk) {
      bf16x8 pa, vf[4];
      pa = *reinterpret_cast<const bf16x8*>(&Ps[w][ln][SWZP(ln, kk * 32 + lh * 8)]);
#pragma unroll
      for (int j = 0; j < 4; ++j) {
        const int vr = j * 16 + ln;
        vf[j] = *reinterpret_cast<const bf16x8*>(&Vts[vr][SWZK(vr, kk * 32 + lh * 8)]);
      }
#pragma unroll
      for (int j = 0; j < 4; ++j)
        o_acc[j] = MFMA(pa, vf[j], o_acc[j]);
    }
  }

  // normalize + store to [B*T][1024]
#pragma unroll
  for (int r = 0; r < 4; ++r) {
    const float inv = 1.0f / l_s[r];
    const int t = q0 + lh * 4 + r;
#pragma unroll
    for (int j = 0; j < 4; ++j) {
      const int d = j * 16 + ln;
      o[(size_t)(b * 2048 + t) * 1024 + h * 64 + d] = (bf16_t)(o_acc[j][r] * inv);
    }
  }
}

// ------------------------------------------------------------- out GEMM ------
__global__ __launch_bounds__(256, 2) void out_gemm(
    const bf16_t* __restrict__ X, const bf16_t* __restrict__ W,
    const float* __restrict__ bias, float* __restrict__ Y) {
  constexpr int Kdim = 1024;
  __shared__ __align__(16) bf16_t As[128][64];
  __shared__ __align__(16) bf16_t Bs[128][64];

  const int tid = threadIdx.x;
  const int lane = tid & 63;
  const int w = tid >> 6;
  const int wr = w >> 1, wc = w & 1;
  const int ln = lane & 15, lh = lane >> 4;
  const int brow = blockIdx.y * 128;
  const int bcol = blockIdx.x * 128;
  const int soff = (w * 4) * 1024 + lane * 16;

  f32x4 acc[4][4] = {};

  for (int k0 = 0; k0 < Kdim; k0 += 64) {
#pragma unroll
    for (int s = 0; s < 4; ++s) {
      const int off = soff + s * 1024;
      const int row = off >> 7, colb = off & 127;
      gload_lds16((const char*)X + ((size_t)(brow + row) * Kdim + k0) * 2 + colb,
                  (char*)&As[0][0] + (w * 4 + s) * 1024);
      gload_lds16((const char*)W + ((size_t)(bcol + row) * Kdim + k0) * 2 + colb,
                  (char*)&Bs[0][0] + (w * 4 + s) * 1024);
    }
    __syncthreads();
#pragma unroll
    for (int kk = 0; kk < 2; ++kk) {
      bf16x8 af[4], bfm[4];
#pragma unroll
      for (int i = 0; i < 4; ++i)
        af[i] = *reinterpret_cast<const bf16x8*>(&As[wr * 64 + i * 16 + ln][kk * 32 + lh * 8]);
#pragma unroll
      for (int j = 0; j < 4; ++j)
        bfm[j] = *reinterpret_cast<const bf16x8*>(&Bs[wc * 64 + j * 16 + ln][kk * 32 + lh * 8]);
#pragma unroll
      for (int i = 0; i < 4; ++i)
#pragma unroll
        for (int j = 0; j < 4; ++j)
          acc[i][j] = MFMA(af[i], bfm[j], acc[i][j]);
    }
    __syncthreads();
  }

#pragma unroll
  for (int i = 0; i < 4; ++i) {
    const int m0 = brow + wr * 64 + i * 16 + lh * 4;
#pragma unroll
    for (int j = 0; j < 4; ++j) {
      const int n = bcol + wc * 64 + j * 16 + ln;
      const float bv = bias[n];
#pragma unroll
      for (int r = 0; r < 4; ++r)
        Y[(size_t)(m0 + r) * 1024 + n] = acc[i][j][r] + bv;
    }
  }
}

// ---------------------------------------------------------------- launch -----
extern "C" void kernel_launch(void* const* d_in, const int* in_sizes, int n_in,
                              void* d_out, int out_size, void* d_ws, size_t ws_size,
                              hipStream_t stream) {
  const float* x  = (const float*)d_in[0];
  const float* Wq = (const float*)d_in[1];
  const float* Wk = (const float*)d_in[2];
  const float* Wv = (const float*)d_in[3];
  const float* Wo = (const float*)d_in[4];
  const float* bo = (const float*)d_in[5];

  char* ws = (char*)d_ws;
  bf16_t* xb  = (bf16_t*)(ws);                        // 8 MB  [4096][1024]
  bf16_t* wqb = (bf16_t*)(ws + (size_t)(8u  << 20));  // 2 MB
  bf16_t* wkb = (bf16_t*)(ws + (size_t)(10u << 20));  // 2 MB
  bf16_t* wvb = (bf16_t*)(ws + (size_t)(12u << 20));  // 2 MB
  bf16_t* wob = (bf16_t*)(ws + (size_t)(14u << 20));  // 2 MB
  bf16_t* qb  = (bf16_t*)(ws + (size_t)(16u << 20));  // 8 MB  [2][16][2048][64]
  bf16_t* kb  = (bf16_t*)(ws + (size_t)(24u << 20));  // 8 MB  [2][16][2048][64]
  bf16_t* vtb = (bf16_t*)(ws + (size_t)(32u << 20));  // 8 MB  [2][16][64][2048]
  bf16_t* ob  = (bf16_t*)(ws + (size_t)(40u << 20));  // 8 MB  [4096][1024]

  cvt_f32_to_bf16<<<2048, 256, 0, stream>>>(x, xb, 4096 * 1024);
  cvt4_f32_to_bf16<<<dim3(512, 4), 256, 0, stream>>>(Wq, Wk, Wv, Wo, wqb, wkb, wvb, wob);

  qkv_gemm<<<dim3(8, 32, 3), 256, 0, stream>>>(xb, wqb, wkb, wvb, qb, kb, vtb);
  attn_fwd<<<dim3(32, 32), 256, 0, stream>>>(qb, kb, vtb, ob);
  out_gemm<<<dim3(8, 32), 256, 0, stream>>>(ob, wob, bo, (float*)d_out);
}